// Round 2
// baseline (1002.658 us; speedup 1.0000x reference)
//
#include <hip/hip_runtime.h>
#include <hip/hip_cooperative_groups.h>

namespace cg = cooperative_groups;

typedef _Float16 half8 __attribute__((ext_vector_type(8)));
typedef _Float16 half4v __attribute__((ext_vector_type(4)));
typedef float f32x4 __attribute__((ext_vector_type(4)));

#define LDK 72   // 64 + 8 halfs: 144 B row stride, 16B-aligned b128, 2-way bank alias (free)

// ---- W1[512][128] f32 -> W1T[128][512] f16 --------------------------------------------------
__global__ void prep_w1t(const float* __restrict__ W1, _Float16* __restrict__ W1T) {
    int idx = blockIdx.x * 256 + threadIdx.x;   // 65536 total
    int n = idx >> 9;          // 0..127
    int k = idx & 511;         // 0..511
    W1T[idx] = (_Float16)W1[k * 128 + n];
}

// ---- fused: scores -> global max -> exp+denom -> weighted segment pool ----------------------
__global__ __launch_bounds__(256, 4) void fused_kernel(
        const float* __restrict__ x, const int* __restrict__ batch,
        const _Float16* __restrict__ W1T, const float* __restrict__ b1,
        const float* __restrict__ W2, const float* __restrict__ b2,
        float* __restrict__ scores, float* __restrict__ partial,
        float* __restrict__ denom, int* __restrict__ starts,
        float* __restrict__ out, int N, int NSEG, int ntiles)
{
    __shared__ __align__(16) _Float16 As[64][LDK];    // 9216 B
    __shared__ __align__(16) _Float16 Bs[128][LDK];   // 18432 B
    __shared__ float red[256];                        // 1024 B  => 28.7 KB total

    cg::grid_group gg = cg::this_grid();
    const int tid = threadIdx.x;
    const int wave = tid >> 6, lane = tid & 63;
    const int quad = lane >> 4, col = lane & 15;
    const long gsz = (long)gridDim.x * 256;
    const long gtid = (long)blockIdx.x * 256 + tid;

    // ================= Phase A: score MLP (x@W1 tanh @W2), block max, starts, denom=0 =======
    float b1v[8], w2v[8];
    #pragma unroll
    for (int nt = 0; nt < 8; ++nt) {
        b1v[nt] = b1[nt * 16 + col];
        w2v[nt] = W2[nt * 16 + col];
    }
    const float bias2 = b2[0];
    float lmax = -1e30f;

    for (int tile = blockIdx.x; tile < ntiles; tile += gridDim.x) {
        const long row0 = (long)tile * 64;
        f32x4 acc[8] = {};
        for (int kc = 0; kc < 512; kc += 64) {
            // stage A: 64 rows x 64 cols fp32 -> fp16 (4 float4 / thread)
            #pragma unroll
            for (int it = 0; it < 4; ++it) {
                int idx = it * 256 + tid;        // 0..1023
                int r = idx >> 4, c4 = idx & 15;
                float4 v = *(const float4*)&x[(row0 + r) * 512 + kc + c4 * 4];
                half4v h;
                h[0] = (_Float16)v.x; h[1] = (_Float16)v.y;
                h[2] = (_Float16)v.z; h[3] = (_Float16)v.w;
                *(half4v*)&As[r][c4 * 4] = h;
            }
            // stage B: W1T 128 n-rows x 64 k (4 half8 / thread)
            #pragma unroll
            for (int it = 0; it < 4; ++it) {
                int idx = it * 256 + tid;        // 0..1023
                int n = idx >> 3, c8 = idx & 7;
                *(half8*)&Bs[n][c8 * 8] = *(const half8*)&W1T[n * 512 + kc + c8 * 8];
            }
            __syncthreads();
            #pragma unroll
            for (int ks = 0; ks < 64; ks += 32) {
                half8 a = *(half8*)&As[wave * 16 + col][ks + quad * 8];
                half8 bf[8];
                #pragma unroll
                for (int nt = 0; nt < 8; ++nt)
                    bf[nt] = *(half8*)&Bs[nt * 16 + col][ks + quad * 8];
                #pragma unroll
                for (int nt = 0; nt < 8; ++nt)
                    acc[nt] = __builtin_amdgcn_mfma_f32_16x16x32_f16(a, bf[nt], acc[nt], 0, 0, 0);
            }
            __syncthreads();
        }
        // epilogue: score = sum_n tanh(h+b1)*W2 + b2 ; C/D: col=lane&15, row=quad*4+r
        #pragma unroll
        for (int r = 0; r < 4; ++r) {
            float p = 0.f;
            #pragma unroll
            for (int nt = 0; nt < 8; ++nt)
                p += tanhf(acc[nt][r] + b1v[nt]) * w2v[nt];
            #pragma unroll
            for (int off = 1; off < 16; off <<= 1) p += __shfl_xor(p, off);
            p += bias2;
            lmax = fmaxf(lmax, p);
            if (col == 0) scores[row0 + wave * 16 + quad * 4 + r] = p;
        }
    }
    // segment start offsets (batch sorted)
    for (long i = gtid; i < N; i += gsz) {
        int s = batch[i];
        int pv = (i == 0) ? -1 : batch[i - 1];
        for (int bb = pv + 1; bb <= s; ++bb) starts[bb] = (int)i;
        if (i == N - 1)
            for (int bb = s + 1; bb <= NSEG; ++bb) starts[bb] = N;
    }
    // zero denominators (ws is poisoned)
    for (long bb = gtid; bb < NSEG; bb += gsz) denom[bb] = 0.f;
    // per-block max -> partial
    red[tid] = lmax;
    __syncthreads();
    for (int s = 128; s > 0; s >>= 1) {
        if (tid < s) red[tid] = fmaxf(red[tid], red[tid + s]);
        __syncthreads();
    }
    if (tid == 0) partial[blockIdx.x] = red[0];
    gg.sync();

    // ================= Phase B: global max; exp + segment denominators ======================
    float m = -1e30f;
    for (int i = tid; i < (int)gridDim.x; i += 256) m = fmaxf(m, partial[i]);
    red[tid] = m;
    __syncthreads();
    for (int s = 128; s > 0; s >>= 1) {
        if (tid < s) red[tid] = fmaxf(red[tid], red[tid + s]);
        __syncthreads();
    }
    const float gm = red[0];
    for (long i = gtid; i < N; i += gsz) {
        int seg = batch[i];
        float e = __expf(scores[i] - gm);
        scores[i] = e;                       // exp_s in place
        float v = e;
        // wave segmented suffix-sum (batch sorted => contiguous runs)
        #pragma unroll
        for (int off = 1; off < 64; off <<= 1) {
            float ov = __shfl_down(v, off);
            int os = __shfl_down(seg, off);
            if (lane + off < 64 && os == seg) v += ov;
        }
        int pseg = __shfl_up(seg, 1);
        if (lane == 0 || pseg != seg) atomicAdd(&denom[seg], v);
    }
    gg.sync();

    // ================= Phase C: out[b] = (1/denom) * sum_i exp_i * x_i =======================
    const int hh = tid >> 7;                // 0 or 1 (row interleave)
    const int c4 = (tid & 127) * 4;         // column (float4)
    float* comb = (float*)As;               // 2 KB scratch, reuse GEMM LDS
    for (int b = blockIdx.x; b < NSEG; b += gridDim.x) {
        const int s0 = starts[b], s1 = starts[b + 1];
        const float dinv = 1.f / (denom[b] + 1e-8f);
        f32x4 acc = {};
        for (int i = s0 + hh; i < s1; i += 2) {
            float w = scores[i];
            const f32x4 xv = *(const f32x4*)&x[(long)i * 512 + c4];
            acc += w * xv;
        }
        __syncthreads();
        if (hh) *(f32x4*)&comb[c4] = acc;
        __syncthreads();
        if (!hh) {
            acc += *(f32x4*)&comb[c4];
            acc *= dinv;
            *(f32x4*)&out[(long)b * 512 + c4] = acc;
        }
    }
}

extern "C" void kernel_launch(void* const* d_in, const int* in_sizes, int n_in,
                              void* d_out, int out_size, void* d_ws, size_t ws_size,
                              hipStream_t stream) {
    const float* x     = (const float*)d_in[0];
    const int*   batch = (const int*)d_in[1];
    const float* W1    = (const float*)d_in[2];
    const float* b1    = (const float*)d_in[3];
    const float* W2    = (const float*)d_in[4];
    const float* b2    = (const float*)d_in[5];
    float* out = (float*)d_out;

    const int N = in_sizes[1];          // 262144
    const int NSEG = out_size / 512;    // 1024
    const int ntiles = N / 64;          // 4096

    // workspace layout (16B-aligned)
    _Float16* W1T  = (_Float16*)d_ws;                    // 128*512*2 = 131072 B
    float* scores  = (float*)((char*)d_ws + 131072);     // N floats (becomes exp_s)
    float* partial = scores + N;                         // <=1024 floats
    float* denom   = partial + 1024;                     // NSEG floats
    int*   starts  = (int*)(denom + NSEG);               // NSEG+1 ints

    prep_w1t<<<256, 256, 0, stream>>>(W1, W1T);

    int nb = 0;
    if (hipOccupancyMaxActiveBlocksPerMultiprocessor(&nb, fused_kernel, 256, 0) != hipSuccess
        || nb < 1)
        nb = 4;                                          // launch_bounds guarantees 4
    long grid = (long)nb * 256;
    if (grid > 1024) grid = 1024;                        // pool wants <= NSEG-ish; tiles grid-stride

    void* args[] = { (void*)&x, (void*)&batch, (void*)&W1T, (void*)&b1, (void*)&W2, (void*)&b2,
                     (void*)&scores, (void*)&partial, (void*)&denom, (void*)&starts,
                     (void*)&out, (void*)&N, (void*)&NSEG, (void*)&ntiles };
    hipLaunchCooperativeKernel((const void*)fused_kernel, dim3((int)grid), dim3(256),
                               args, 0, stream);
}

// Round 3
// 900.830 us; speedup vs baseline: 1.1130x; 1.1130x over previous
//
#include <hip/hip_runtime.h>

typedef _Float16 half8 __attribute__((ext_vector_type(8)));
typedef _Float16 half4v __attribute__((ext_vector_type(4)));
typedef float f32x4 __attribute__((ext_vector_type(4)));

#define NPAD 520   // 512 + 8 halfs pad: row stride 1040 B keeps b128 frag reads at the 8-touch minimum

__device__ __forceinline__ float tanh_fast(float v) {
    // 1 - 2/(e^{2v}+1); exact at +-inf overflow, ~1e-7 abs err — far below fp16 noise
    float e = __expf(2.f * v);
    return 1.f - 2.f / (e + 1.f);
}

// ---- K0: W1[512][128] f32 -> W1T[128][512] f16, and zero out_acc+denom (ws is poisoned) -----
__global__ void init_kernel(const float* __restrict__ W1, _Float16* __restrict__ W1T,
                            float* __restrict__ zero_base, int nzero4) {
    int b = blockIdx.x;
    if (b < 256) {
        int idx = b * 256 + threadIdx.x;       // 65536 = n*512+k
        int n = idx >> 9, k = idx & 511;
        W1T[idx] = (_Float16)W1[k * 128 + n];
    } else {
        f32x4 z = {};
        for (int i = (b - 256) * 256 + threadIdx.x; i < nzero4; i += 256 * 256)
            *(f32x4*)&zero_base[(long)i * 4] = z;
    }
}

// ---- K1: per 64-row tile: scores (MFMA) -> exp -> denom atomics -> sum(exp*x) atomics -------
// No max-shift: weight is invariant to the global shift (same constant in num & denom), and
// scores are tanh-bounded (|s| <~ 10) so raw expf is fp32-safe.
__global__ __launch_bounds__(256, 2) void fused_kernel(
        const float* __restrict__ x, const int* __restrict__ batch,
        const _Float16* __restrict__ W1T, const float* __restrict__ b1,
        const float* __restrict__ W2, const float* __restrict__ b2,
        float* __restrict__ out_acc, float* __restrict__ denom)
{
    __shared__ __align__(16) _Float16 As[64][NPAD];   // full 64x512 x-tile fp16: 66.56 KB
    __shared__ float exp_lds[64];
    __shared__ int batch_lds[64];

    const int tid = threadIdx.x;
    const int wv = tid >> 6, lane = tid & 63;
    const int quad = lane >> 4, col = lane & 15;
    const long row0 = (long)blockIdx.x * 64;

    if (tid < 64) batch_lds[tid] = (int)batch[row0 + tid];

    // stage whole tile: 64 rows x 512 cols fp32 -> fp16 (32 float4 per thread, coalesced 1KB/wave)
    #pragma unroll 8
    for (int it = 0; it < 32; ++it) {
        int f = it * 256 + tid;             // float4 index 0..8191
        int r = f >> 7, cf = f & 127;
        float4 v = *(const float4*)&x[(row0 + r) * 512 + cf * 4];
        half4v h;
        h[0] = (_Float16)v.x; h[1] = (_Float16)v.y;
        h[2] = (_Float16)v.z; h[3] = (_Float16)v.w;
        *(half4v*)&As[r][cf * 4] = h;       // 8B/lane consecutive: 2-way bank alias = free
    }
    __syncthreads();

    // ---- MFMA: h = x-tile @ W1 ; A from LDS, B direct from L2-hot W1T ----
    f32x4 acc[8] = {};
    #pragma unroll 4
    for (int ks = 0; ks < 16; ++ks) {
        half8 a = *(const half8*)&As[wv * 16 + col][ks * 32 + quad * 8];
        half8 bf[8];
        #pragma unroll
        for (int nt = 0; nt < 8; ++nt)
            bf[nt] = *(const half8*)&W1T[(nt * 16 + col) * 512 + ks * 32 + quad * 8];
        #pragma unroll
        for (int nt = 0; nt < 8; ++nt)
            acc[nt] = __builtin_amdgcn_mfma_f32_16x16x32_f16(a, bf[nt], acc[nt], 0, 0, 0);
    }

    // ---- epilogue: score -> exp, into LDS (C/D: n=col=lane&15, m=quad*4+r) ----
    {
        float b1v[8], w2v[8];
        #pragma unroll
        for (int nt = 0; nt < 8; ++nt) {
            b1v[nt] = b1[nt * 16 + col];
            w2v[nt] = W2[nt * 16 + col];
        }
        const float bias2 = b2[0];
        #pragma unroll
        for (int r = 0; r < 4; ++r) {
            float p = 0.f;
            #pragma unroll
            for (int nt = 0; nt < 8; ++nt)
                p += tanh_fast(acc[nt][r] + b1v[nt]) * w2v[nt];
            #pragma unroll
            for (int off = 1; off < 16; off <<= 1) p += __shfl_xor(p, off);
            if (col == 0)
                exp_lds[wv * 16 + quad * 4 + r] = __expf(p + bias2);
        }
    }
    __syncthreads();

    // ---- denominator: wave 0 segmented-reduces the 64 exps (~1-3 atomics/block) ----
    if (tid < 64) {
        int seg = batch_lds[tid];
        float v = exp_lds[tid];
        #pragma unroll
        for (int off = 1; off < 64; off <<= 1) {
            float ov = __shfl_down(v, off);
            int os = __shfl_down(seg, off);
            if (lane + off < 64 && os == seg) v += ov;
        }
        int pseg = __shfl_up(seg, 1);
        if (tid == 0 || pseg != seg) atomicAdd(&denom[seg], v);
    }

    // ---- weighted accumulate: out_acc[seg][c] += exp_j * x[j][c], x re-read from LDS fp16 ----
    {
        const int h2 = tid >> 7;            // row interleave 0/1
        const int cg = tid & 127;           // column group (4 floats)
        f32x4 wacc = {};
        int cur = batch_lds[h2];
        for (int j = h2; j < 64; j += 2) {
            int s = batch_lds[j];
            if (s != cur) {                 // wave-uniform branch (boundaries at shared j)
                #pragma unroll
                for (int k2 = 0; k2 < 4; ++k2)
                    atomicAdd(&out_acc[(long)cur * 512 + cg * 4 + k2], wacc[k2]);
                wacc = (f32x4){};
                cur = s;
            }
            float w = exp_lds[j];
            half4v xh = *(const half4v*)&As[j][cg * 4];
            wacc[0] += w * (float)xh[0];
            wacc[1] += w * (float)xh[1];
            wacc[2] += w * (float)xh[2];
            wacc[3] += w * (float)xh[3];
        }
        #pragma unroll
        for (int k2 = 0; k2 < 4; ++k2)
            atomicAdd(&out_acc[(long)cur * 512 + cg * 4 + k2], wacc[k2]);
    }
}

// ---- K2: out = out_acc / (denom + 1e-8) ----------------------------------------------------
__global__ void finalize_kernel(const float* __restrict__ out_acc,
                                const float* __restrict__ denom,
                                float* __restrict__ out) {
    int i = blockIdx.x * 256 + threadIdx.x;         // float4 index, 131072 total
    f32x4 v = *(const f32x4*)&out_acc[(long)i * 4];
    float d = 1.f / (denom[i >> 7] + 1e-8f);        // element (i*4)>>9
    *(f32x4*)&out[(long)i * 4] = v * d;
}

extern "C" void kernel_launch(void* const* d_in, const int* in_sizes, int n_in,
                              void* d_out, int out_size, void* d_ws, size_t ws_size,
                              hipStream_t stream) {
    const float* x     = (const float*)d_in[0];
    const int*   batch = (const int*)d_in[1];
    const float* W1    = (const float*)d_in[2];
    const float* b1    = (const float*)d_in[3];
    const float* W2    = (const float*)d_in[4];
    const float* b2    = (const float*)d_in[5];
    float* out = (float*)d_out;

    const int N = in_sizes[1];             // 262144
    const int NSEG = out_size / 512;       // 1024

    // ws layout (16B-aligned): W1T | out_acc | denom (out_acc+denom zeroed together)
    _Float16* W1T   = (_Float16*)d_ws;                       // 131072 B
    float* out_acc  = (float*)((char*)d_ws + 131072);        // 524288 floats
    float* denom    = out_acc + (long)NSEG * 512;            // NSEG floats

    const int nzero4 = (NSEG * 512 + NSEG) / 4;              // 131328 float4s

    init_kernel<<<512, 256, 0, stream>>>(W1, W1T, out_acc, nzero4);
    fused_kernel<<<N / 64, 256, 0, stream>>>(x, batch, W1T, b1, W2, b2, out_acc, denom);
    finalize_kernel<<<out_size / 1024, 256, 0, stream>>>(out_acc, denom, out);
}